// Round 1
// 2999.836 us; speedup vs baseline: 1.2036x; 1.2036x over previous
//
#include <hip/hip_runtime.h>

#define BB 256
#define LL 2048
#define DIN 128
#define DOUT 128
#define T 32          // timesteps per chunk
#define NTHREADS 512
#define TT 8          // per-thread t-range in projection phase (T/4)

__device__ __forceinline__ float tanh_fast(float v) {
    // algebraically exact: tanh(v) = 1 - 2/(exp(2v)+1); abs err ~1e-7
    float e = __expf(2.0f * v);
    return 1.0f - 2.0f / (e + 1.0f);
}

__global__ __launch_bounds__(NTHREADS, 2)
void rwa_fused(const float* __restrict__ x, const float* __restrict__ s0,
               const float* __restrict__ u_w, const float* __restrict__ u_b,
               const float* __restrict__ g_w, const float* __restrict__ g_b,
               const float* __restrict__ a_w, float* __restrict__ out)
{
    __shared__ float x_sh[T * DIN];     // 16 KB
    __shared__ float pU[T * DOUT];      // 16 KB (reused as h output buffer)
    __shared__ float pG[T * DOUT];      // 16 KB
    __shared__ float pA[T * DOUT];      // 16 KB
    __shared__ float h_sh[DOUT];
    __shared__ float psum[3 * DOUT];    // [0]=g-half1, [1]=a-half0, [2]=a-half1

    const int tid  = threadIdx.x;
    const int o    = tid & 127;
    const int sel  = tid >> 7;          // 0..3
    const int side = sel >> 1;          // 0 = g-side, 1 = a-side
    const int half = sel & 1;           // which 64-wide half of h
    const int b    = blockIdx.x;

    // ---- recurrence weight HALF-row for this thread: 16 float4 = 64 VGPRs ----
    // side0: g_wh[o][half*64 .. +64) ; side1: a_wh[o][half*64 .. +64)
    float4 wreg[16];
    {
        const float* wbase = (side == 0 ? g_w : a_w)
                           + (size_t)o * (DIN + DOUT) + DIN + half * 64;
        const float4* wsrc = (const float4*)wbase;
        #pragma unroll
        for (int i = 0; i < 16; i++) wreg[i] = wsrc[i];
    }
    const float ub = u_b[o];
    const float gb = g_b[o];

    // ---- init state (held by sel==0 threads) ----
    float num = 0.0f, den = 0.0f, amax = 1e-38f;
    if (tid < DOUT) h_sh[tid] = tanh_fast(s0[tid]);
    __syncthreads();

    const float4* u4 = (const float4*)(u_w + (size_t)o * DIN);
    const float4* g4 = (const float4*)(g_w + (size_t)o * (DIN + DOUT));
    const float4* a4 = (const float4*)(a_w + (size_t)o * (DIN + DOUT));

    for (int t0 = 0; t0 < LL; t0 += T) {
        // ---- stage x chunk: x[b, t0..t0+T, :] -> LDS (coalesced float4) ----
        {
            const float4* xg = (const float4*)(x + ((size_t)b * LL + t0) * DIN);
            float4* xs = (float4*)x_sh;
            #pragma unroll
            for (int i = 0; i < (T * DIN / 4) / NTHREADS; i++)   // 2 iters
                xs[tid + NTHREADS * i] = xg[tid + NTHREADS * i];
        }
        __syncthreads();

        // ---- projections: thread (o, sel) computes row o of U/Gx/Ax for
        //      t in [sel*TT, sel*TT+TT). x reads are wave-uniform broadcasts.
        {
            float accU[TT], accG[TT], accA[TT];
            #pragma unroll
            for (int tt = 0; tt < TT; tt++) { accU[tt] = ub; accG[tt] = gb; accA[tt] = 0.0f; }
            const float4* xs4 = (const float4*)x_sh + (size_t)(sel * TT) * 32;
            #pragma unroll 2
            for (int k4 = 0; k4 < 32; k4++) {
                float4 wu = u4[k4], wg = g4[k4], wa = a4[k4];
                #pragma unroll
                for (int tt = 0; tt < TT; tt++) {
                    float4 xv = xs4[tt * 32 + k4];
                    accU[tt] = fmaf(wu.x, xv.x, fmaf(wu.y, xv.y, fmaf(wu.z, xv.z, fmaf(wu.w, xv.w, accU[tt]))));
                    accG[tt] = fmaf(wg.x, xv.x, fmaf(wg.y, xv.y, fmaf(wg.z, xv.z, fmaf(wg.w, xv.w, accG[tt]))));
                    accA[tt] = fmaf(wa.x, xv.x, fmaf(wa.y, xv.y, fmaf(wa.z, xv.z, fmaf(wa.w, xv.w, accA[tt]))));
                }
            }
            #pragma unroll
            for (int tt = 0; tt < TT; tt++) {
                int t = sel * TT + tt;
                pU[t * DOUT + o] = accU[tt];
                pG[t * DOUT + o] = accG[tt];
                pA[t * DOUT + o] = accA[tt];
            }
        }
        __syncthreads();

        // ---- sequential recurrence over this chunk ----
        for (int ts = 0; ts < T; ts++) {
            // each thread: partial dot over its 64-wide half of h.
            // hv preload: 16 pipelined broadcast ds_read_b128 (regs available now
            // that wreg is only 64 VGPRs), then FMA chain on 4 accumulators.
            float4 hv[16];
            const float4* h4 = (const float4*)h_sh + half * 16;
            #pragma unroll
            for (int i = 0; i < 16; i++) hv[i] = h4[i];
            float ax0 = 0.f, ax1 = 0.f, ax2 = 0.f, ax3 = 0.f;
            #pragma unroll
            for (int i = 0; i < 16; i++) {
                ax0 = fmaf(wreg[i].x, hv[i].x, ax0);
                ax1 = fmaf(wreg[i].y, hv[i].y, ax1);
                ax2 = fmaf(wreg[i].z, hv[i].z, ax2);
                ax3 = fmaf(wreg[i].w, hv[i].w, ax3);
            }
            float part = (ax0 + ax1) + (ax2 + ax3);
            if (sel != 0) psum[(sel - 1) * DOUT + o] = part;
            __syncthreads();   // partials ready; all h_sh reads complete
            if (sel == 0) {
                float gdot = part + psum[o];
                float adot = psum[DOUT + o] + psum[2 * DOUT + o];
                float g = tanh_fast(pG[ts * DOUT + o] + gdot);
                float z = pU[ts * DOUT + o] * g;
                float a = pA[ts * DOUT + o] + adot;
                float amn = fmaxf(a, amax);
                float e = __expf(amn - amax);
                amax = amn;
                num = fmaf(z, e, num);
                den += e;
                float h = tanh_fast(num / den);
                h_sh[o] = h;
                pU[ts * DOUT + o] = h;   // pU[ts] is dead now: reuse as h buffer
            }
            __syncthreads();   // h ready for next step
        }

        // ---- coalesced chunk store: pU holds h for t0..t0+T ----
        // (last ts barrier made pU writes visible; the global stores drain at
        //  the NEXT chunk's stage barrier, off the per-timestep critical path)
        {
            float4* og = (float4*)(out + ((size_t)b * LL + t0) * DOUT);
            const float4* hs = (const float4*)pU;
            #pragma unroll
            for (int i = 0; i < (T * DOUT / 4) / NTHREADS; i++)   // 2 iters
                og[tid + NTHREADS * i] = hs[tid + NTHREADS * i];
        }
    }
}

extern "C" void kernel_launch(void* const* d_in, const int* in_sizes, int n_in,
                              void* d_out, int out_size, void* d_ws, size_t ws_size,
                              hipStream_t stream) {
    const float* x   = (const float*)d_in[0];
    const float* s0  = (const float*)d_in[1];
    const float* u_w = (const float*)d_in[2];
    const float* u_b = (const float*)d_in[3];
    const float* g_w = (const float*)d_in[4];
    const float* g_b = (const float*)d_in[5];
    const float* a_w = (const float*)d_in[6];
    float* out = (float*)d_out;
    rwa_fused<<<BB, NTHREADS, 0, stream>>>(x, s0, u_w, u_b, g_w, g_b, a_w, out);
}